// Round 1
// baseline (6506.190 us; speedup 1.0000x reference)
//
#include <hip/hip_runtime.h>
#include <math.h>

#define IMG_W 96
#define IMG_H 96
#define HWSZ  9216          // 96*96
#define CCH   128
#define BATCH 8
#define NT    4

#define XS_ELEMS (BATCH*CCH*HWSZ)     // one timestep slice = 9,437,184
#define ES_OFF   (4*XS_ELEMS)

// ---------------------------------------------------------------------------
// GroupNorm stats: one block per (b, group). Group = 2 adjacent channels,
// contiguous 18432 floats. Outputs (mu, rstd) per group into ws.
// ---------------------------------------------------------------------------
__global__ __launch_bounds__(256) void gn_stats_kernel(
    const float* __restrict__ c, float* __restrict__ stats)
{
    const int bg  = blockIdx.x;              // 0..511 = b*64+g
    const int tid = threadIdx.x;
    const float4* p4 = (const float4*)(c + (size_t)bg * 18432);
    float s1 = 0.f, s2 = 0.f;
    for (int i = tid; i < 18432/4; i += 256) {
        float4 v = p4[i];
        s1 += v.x + v.y + v.z + v.w;
        s2 += v.x*v.x + v.y*v.y + v.z*v.z + v.w*v.w;
    }
    __shared__ float r1[256], r2[256];
    r1[tid] = s1; r2[tid] = s2;
    __syncthreads();
    for (int s = 128; s > 0; s >>= 1) {
        if (tid < s) { r1[tid] += r1[tid+s]; r2[tid] += r2[tid+s]; }
        __syncthreads();
    }
    if (tid == 0) {
        float mu  = r1[0] * (1.f/18432.f);
        float var = r2[0] * (1.f/18432.f) - mu*mu;
        var = fmaxf(var, 0.f);
        stats[bg*2]   = mu;
        stats[bg*2+1] = rsqrtf(var + 1e-5f);
    }
}

// ---------------------------------------------------------------------------
// Fused 7x7 conv (128->128, pad 3) + Kuramoto step + energy.
// Block: 256 threads = 16x16 output pixels x 16 output channels.
//   tid = pxg(0..63) + 64*ocg(0..3); pxg -> row ry=pxg>>2, strip sx=pxg&3.
//   Thread computes 4 consecutive px (cols 4sx..4sx+3) x 4 oc (ocg*4..+3).
// Loops over 64 input-channel PAIRS (so FIRST can normalize staged input).
// ---------------------------------------------------------------------------
template<bool FIRST>
__global__ __launch_bounds__(256) void conv_kur_kernel(
    const float* __restrict__ xin,    // FIRST: raw x; else previous xs slice
    const float* __restrict__ craw,   // raw c
    const float* __restrict__ cw,     // conv_w [128][128][7][7]
    const float* __restrict__ cb,     // conv_b [128]
    const float* __restrict__ gnw,
    const float* __restrict__ gnb,
    const float* __restrict__ omega,
    const float* __restrict__ stats,  // (mu,rstd) per (b,g)
    float* __restrict__ xout,         // xs slice t
    float* __restrict__ es)           // energies row es[t+1][...]
{
    __shared__ float s_in[2][22][24];     // 2 channels, 22 rows, padded stride 24
    __shared__ float s_w[2][49][16];      // 2 channels, 49 taps, 16 oc
    __shared__ float s_red[256];

    const int tid  = threadIdx.x;
    const int tile = blockIdx.x;          // 0..35
    const int ocb  = blockIdx.y;          // 0..7
    const int b    = blockIdx.z;          // 0..7

    const int row0 = (tile / 6) * 16;
    const int col0 = (tile % 6) * 16;

    const int pxg = tid & 63;
    const int ocg = tid >> 6;             // wave id -> wave-uniform weights
    const int ry  = pxg >> 2;
    const int sx  = pxg & 3;

    const size_t in_base = (size_t)b * CCH * HWSZ;

    float acc[4][4] = {};

    for (int icp = 0; icp < 64; ++icp) {
        __syncthreads();   // previous iteration's LDS reads done
        // ---- stage input tile: 2 channels x 22x22 (zero-padded) ----
        for (int idx = tid; idx < 968; idx += 256) {
            int ch  = idx / 484;
            int rem = idx - ch * 484;
            int r   = rem / 22;
            int cl  = rem - r * 22;
            int gr  = row0 + r - 3, gc = col0 + cl - 3;
            float v = 0.f;
            if (gr >= 0 && gr < IMG_H && gc >= 0 && gc < IMG_W)
                v = xin[in_base + (size_t)(icp*2 + ch) * HWSZ + gr*IMG_W + gc];
            s_in[ch][r][cl] = v;
        }
        // ---- stage weights: 2 ch x 49 taps x 16 oc ----
        {
            int combo = tid & 31;          // ch*16 + j
            int q     = tid >> 5;          // 0..7 (q==7 idle)
            if (q < 7) {
                int ch = combo >> 4, j = combo & 15;
                const float* wp = cw + ((size_t)(ocb*16 + j) * CCH + icp*2 + ch) * 49 + q*7;
                #pragma unroll
                for (int t7 = 0; t7 < 7; ++t7)
                    s_w[ch][q*7 + t7][j] = wp[t7];
            }
        }
        __syncthreads();
        if (FIRST) {   // normalize oscillator pairs in the staged tile
            for (int idx = tid; idx < 484; idx += 256) {
                int r  = idx / 22;
                int cl = idx - r * 22;
                float v0 = s_in[0][r][cl], v1 = s_in[1][r][cl];
                float sc = 1.f / fmaxf(sqrtf(v0*v0 + v1*v1), 1e-12f);
                s_in[0][r][cl] = v0 * sc;
                s_in[1][r][cl] = v1 * sc;
            }
            __syncthreads();
        }
        // ---- compute: 2 ch x 49 taps x (4 oc x 4 px) ----
        #pragma unroll
        for (int ch = 0; ch < 2; ++ch) {
            #pragma unroll
            for (int dy = 0; dy < 7; ++dy) {
                float r[12];
                const float* rp = &s_in[ch][ry + dy][sx * 4];   // 16B aligned
                #pragma unroll
                for (int i = 0; i < 12; ++i) r[i] = rp[i];
                #pragma unroll
                for (int dx = 0; dx < 7; ++dx) {
                    const float* wv = &s_w[ch][dy*7 + dx][ocg*4];  // wave-uniform
                    float w0 = wv[0], w1 = wv[1], w2 = wv[2], w3 = wv[3];
                    #pragma unroll
                    for (int p = 0; p < 4; ++p) {
                        float iv = r[dx + p];
                        acc[0][p] = fmaf(w0, iv, acc[0][p]);
                        acc[1][p] = fmaf(w1, iv, acc[1][p]);
                        acc[2][p] = fmaf(w2, iv, acc[2][p]);
                        acc[3][p] = fmaf(w3, iv, acc[3][p]);
                    }
                }
            }
        }
    }

    // ---- epilogue: Kuramoto update on 2 oscillator pairs x 4 px ----
    const int   py  = row0 + ry;
    const int   px0 = col0 + sx * 4;
    const float om  = omega[0];
    const int   ocbase = ocb*16 + ocg*4;
    float esum = 0.f;

    #pragma unroll
    for (int pr = 0; pr < 2; ++pr) {
        const int oc0 = ocbase + pr*2;
        const int g   = oc0 >> 1;
        const float mu = stats[(b*64 + g)*2];
        const float rs = stats[(b*64 + g)*2 + 1];
        const float w0s = gnw[oc0]   * rs, b0s = gnb[oc0]   - mu * rs * gnw[oc0];
        const float w1s = gnw[oc0+1] * rs, b1s = gnb[oc0+1] - mu * rs * gnw[oc0+1];
        const float cb0 = cb[oc0], cb1 = cb[oc0+1];
        const size_t off = in_base + (size_t)oc0 * HWSZ + py*IMG_W + px0;
        const float* c0p = craw + off;  const float* c1p = c0p + HWSZ;
        const float* x0p = xin  + off;  const float* x1p = x0p + HWSZ;
        float*       o0p = xout + off;  float*       o1p = o0p + HWSZ;
        #pragma unroll
        for (int p = 0; p < 4; ++p) {
            float x0 = x0p[p], x1 = x1p[p];
            if (FIRST) {
                float sc = 1.f / fmaxf(sqrtf(x0*x0 + x1*x1), 1e-12f);
                x0 *= sc; x1 *= sc;
            }
            float y0 = acc[pr*2][p]   + cb0 + fmaf(c0p[p], w0s, b0s);
            float y1 = acc[pr*2+1][p] + cb1 + fmaf(c1p[p], w1s, b1s);
            float inner = x0*y0 + x1*y1;
            esum += inner;
            float xn0 = x0 - om*x1 + (y0 - inner*x0);
            float xn1 = x1 + om*x0 + (y1 - inner*x1);
            float sc2 = 1.f / fmaxf(sqrtf(xn0*xn0 + xn1*xn1), 1e-12f);
            o0p[p] = xn0 * sc2;
            o1p[p] = xn1 * sc2;
        }
    }

    // ---- energy: block reduce, one atomic per block ----
    s_red[tid] = esum;
    __syncthreads();
    for (int s = 128; s > 0; s >>= 1) {
        if (tid < s) s_red[tid] += s_red[tid + s];
        __syncthreads();
    }
    if (tid == 0) atomicAdd(es + b, -s_red[0]);
}

// ---------------------------------------------------------------------------
extern "C" void kernel_launch(void* const* d_in, const int* in_sizes, int n_in,
                              void* d_out, int out_size, void* d_ws, size_t ws_size,
                              hipStream_t stream)
{
    const float* x   = (const float*)d_in[0];
    const float* c   = (const float*)d_in[1];
    const float* cw  = (const float*)d_in[2];
    const float* cb  = (const float*)d_in[3];
    const float* gnw = (const float*)d_in[4];
    const float* gnb = (const float*)d_in[5];
    const float* om  = (const float*)d_in[6];
    float* out   = (float*)d_out;
    float* stats = (float*)d_ws;       // 512*2 floats

    // zero all 40 energy outputs (es[0] row stays zero; rest accumulated)
    hipMemsetAsync(out + ES_OFF, 0, 40 * sizeof(float), stream);

    gn_stats_kernel<<<512, 256, 0, stream>>>(c, stats);

    dim3 grid(36, 8, 8);
    const float* xin = x;
    for (int t = 0; t < NT; ++t) {
        float* xo  = out + (size_t)t * XS_ELEMS;
        float* esl = out + ES_OFF + (t + 1) * 8;
        if (t == 0)
            conv_kur_kernel<true ><<<grid, 256, 0, stream>>>(xin, c, cw, cb, gnw, gnb, om, stats, xo, esl);
        else
            conv_kur_kernel<false><<<grid, 256, 0, stream>>>(xin, c, cw, cb, gnw, gnb, om, stats, xo, esl);
        xin = xo;
    }
}

// Round 2
// 717.930 us; speedup vs baseline: 9.0624x; 9.0624x over previous
//
#include <hip/hip_runtime.h>
#include <math.h>

typedef unsigned short u16;
typedef unsigned int   u32;
typedef __attribute__((ext_vector_type(8))) short bf16x8;
typedef __attribute__((ext_vector_type(4))) float f32x4;

#define IMG_W 96
#define IMG_H 96
#define HWSZ  9216
#define CCH   128
#define BATCH 8
#define NT    4

#define PADW  102
#define PADA  (102*102)            // 10404 pixels per padded image
#define XBF_ELEMS ((size_t)BATCH*PADA*CCH)        // 10,653,696
#define XBF_BYTES (XBF_ELEMS*2)                   // 21,307,392

#define XS_ELEMS (BATCH*CCH*HWSZ)  // 9,437,184
#define ES_OFF   (4*XS_ELEMS)

__device__ inline u16 f2bf(float f) {
    u32 u = __float_as_uint(f);
    u += 0x7fffu + ((u >> 16) & 1u);   // round-to-nearest-even
    return (u16)(u >> 16);
}

#define GLD_LDS16(g, l) \
    __builtin_amdgcn_global_load_lds((const __attribute__((address_space(1))) void*)(g), \
                                     (__attribute__((address_space(3))) void*)(l), 16, 0, 0)

// ---------------------------------------------------------------------------
// GroupNorm stats: one block per (b, group of 2 channels) -> (mu, rstd)
// ---------------------------------------------------------------------------
__global__ __launch_bounds__(256) void gn_stats_kernel(
    const float* __restrict__ c, float* __restrict__ stats)
{
    const int bg  = blockIdx.x;              // b*64+g
    const int tid = threadIdx.x;
    const float4* p4 = (const float4*)(c + (size_t)bg * 18432);
    float s1 = 0.f, s2 = 0.f;
    for (int i = tid; i < 18432/4; i += 256) {
        float4 v = p4[i];
        s1 += v.x + v.y + v.z + v.w;
        s2 += v.x*v.x + v.y*v.y + v.z*v.z + v.w*v.w;
    }
    __shared__ float r1[256], r2[256];
    r1[tid] = s1; r2[tid] = s2;
    __syncthreads();
    for (int s = 128; s > 0; s >>= 1) {
        if (tid < s) { r1[tid] += r1[tid+s]; r2[tid] += r2[tid+s]; }
        __syncthreads();
    }
    if (tid == 0) {
        float mu  = r1[0] * (1.f/18432.f);
        float var = fmaxf(r2[0] * (1.f/18432.f) - mu*mu, 0.f);
        stats[bg*2]   = mu;
        stats[bg*2+1] = rsqrtf(var + 1e-5f);
    }
}

// ---------------------------------------------------------------------------
// Weight reorder: conv_w f32 [oc][ic][7][7] -> wbf bf16 [tap][oc][ic]
// ---------------------------------------------------------------------------
__global__ __launch_bounds__(256) void wprep_kernel(
    const float* __restrict__ cw, u16* __restrict__ wbf)
{
    int idx = blockIdx.x * 256 + threadIdx.x;
    if (idx >= 128*128*49) return;
    int tap = idx % 49;
    int rem = idx / 49;
    int ic  = rem % 128;
    int oc  = rem / 128;
    wbf[(size_t)tap*16384 + oc*128 + ic] = f2bf(cw[idx]);
}

// ---------------------------------------------------------------------------
// x0 prep: normalize oscillator pairs, write bf16 channels-last padded layout
// idx = (b, pix) * 64 pair-lanes  (g fastest -> coalesced 4B writes)
// ---------------------------------------------------------------------------
__global__ __launch_bounds__(256) void xprep_kernel(
    const float* __restrict__ x, u16* __restrict__ xbf)
{
    int idx = blockIdx.x * 256 + threadIdx.x;
    if (idx >= BATCH*HWSZ*64) return;
    int g   = idx & 63;
    int rem = idx >> 6;
    int pix = rem % HWSZ;
    int b   = rem / HWSZ;
    float x0 = x[((size_t)b*CCH + 2*g    )*HWSZ + pix];
    float x1 = x[((size_t)b*CCH + 2*g + 1)*HWSZ + pix];
    float sc = 1.f / fmaxf(sqrtf(x0*x0 + x1*x1), 1e-12f);
    int py = pix / 96, px = pix - py*96;
    size_t o = ((size_t)b*PADA + (py+3)*PADW + (px+3))*128 + 2*g;
    u32 pk = (u32)f2bf(x0*sc) | ((u32)f2bf(x1*sc) << 16);
    *(u32*)(xbf + o) = pk;
}

// ---------------------------------------------------------------------------
// Fused implicit-GEMM conv (bf16 MFMA) + Kuramoto step + energy.
// Block: 256 thr = 4 waves (2x2), tile 128 px x 128 oc, K-step 64 ic,
// 49 taps x 2 halves = 98 K-steps. A/B staged via global_load_lds with
// XOR(granule, row&7) source pre-swizzle; swizzled ds_read_b128 frags.
// ---------------------------------------------------------------------------
template<bool FIRST, bool WRITE_BF>
__global__ __launch_bounds__(256, 2) void convk(
    const u16*   __restrict__ xbf_in,
    const float* __restrict__ xin,     // FIRST: raw x; else xs[t-1] (NCHW f32)
    const float* __restrict__ craw,
    const u16*   __restrict__ wbf,
    const float* __restrict__ cb,
    const float* __restrict__ gnw, const float* __restrict__ gnb,
    const float* __restrict__ omega, const float* __restrict__ stats,
    float* __restrict__ xout, u16* __restrict__ xbf_out,
    float* __restrict__ es)
{
    __shared__ __align__(16) u16 s_a[128*64];
    __shared__ __align__(16) u16 s_b[128*64];
    __shared__ float s_red[256];

    const int tid = threadIdx.x;
    const int w   = tid >> 6;          // wave 0..3
    const int l   = tid & 63;
    const int b   = blockIdx.y;
    const int p0  = blockIdx.x * 128;  // pixel tile base

    const int lrow = l >> 3;           // 0..7
    const int lg   = l & 7;
    const int gsw  = lg ^ lrow;        // source granule (XOR pre-swizzle)

    // staging source pointers (tap (3,3) center, h=0), one per 8-row chunk
    const u16* asrc[4];
    const u16* bsrc[4];
    #pragma unroll
    for (int i = 0; i < 4; ++i) {
        int m  = w*32 + i*8 + lrow;
        int p  = p0 + m;
        int py = p / 96, px = p - py*96;
        asrc[i] = xbf_in + ((size_t)b*PADA + (py+3)*PADW + (px+3))*128 + gsw*8;
        bsrc[i] = wbf + (size_t)(w*32 + i*8 + lrow)*128 + gsw*8;
    }

    f32x4 acc[4][4] = {};
    const int wm = w >> 1, wn = w & 1;
    const int l15 = l & 15, l4 = l >> 4, l7 = l & 7;

    for (int tap = 0; tap < 49; ++tap) {
        const int dy = tap/7 - 3, dx = tap - (tap/7)*7 - 3;
        const int adel = (dy*PADW + dx)*128;
        const int bdel = tap*16384;
        #pragma unroll
        for (int h = 0; h < 2; ++h) {
            __syncthreads();           // previous compute done with LDS
            #pragma unroll
            for (int i = 0; i < 4; ++i) {
                GLD_LDS16(asrc[i] + adel + h*64, s_a + (w*32 + i*8)*64);
                GLD_LDS16(bsrc[i] + bdel + h*64, s_b + (w*32 + i*8)*64);
            }
            __syncthreads();           // vmcnt(0) drained by compiler
            #pragma unroll
            for (int ks = 0; ks < 2; ++ks) {
                bf16x8 af[4], bfr[4];
                const int gd = ks*4 + l4;
                #pragma unroll
                for (int mi = 0; mi < 4; ++mi) {
                    int m = wm*64 + mi*16 + l15;
                    af[mi] = *(const bf16x8*)(s_a + m*64 + ((gd ^ l7) * 8));
                }
                #pragma unroll
                for (int ni = 0; ni < 4; ++ni) {
                    int oc = wn*64 + ni*16 + l15;
                    bfr[ni] = *(const bf16x8*)(s_b + oc*64 + ((gd ^ l7) * 8));
                }
                #pragma unroll
                for (int mi = 0; mi < 4; ++mi)
                    #pragma unroll
                    for (int ni = 0; ni < 4; ++ni)
                        acc[mi][ni] = __builtin_amdgcn_mfma_f32_16x16x32_bf16(
                            af[mi], bfr[ni], acc[mi][ni], 0, 0, 0);
            }
        }
    }

    // ---- epilogue: Kuramoto update; D layout col=lane&15(oc), row=(l>>4)*4+j(px)
    const float om = omega[0];
    const size_t nb = (size_t)b * (CCH*HWSZ);
    float esum = 0.f;

    #pragma unroll
    for (int mi = 0; mi < 4; ++mi) {
        const int pxi = p0 + wm*64 + mi*16 + l4*4;   // 4 consecutive px
        #pragma unroll
        for (int ni = 0; ni < 4; ++ni) {
            const int oc = wn*64 + ni*16 + l15;
            const int g  = oc >> 1;
            const float mu = stats[(b*64+g)*2], rs = stats[(b*64+g)*2+1];
            const float gw = gnw[oc];
            const float wsc = gw*rs, bsc = gnb[oc] - mu*rs*gw;
            const float cbv = cb[oc];
            const f32x4 c4  = *(const f32x4*)(craw + nb + (size_t)oc*HWSZ + pxi);
            f32x4 x4o = *(const f32x4*)(xin + nb + (size_t)oc*HWSZ + pxi);
            f32x4 x4p = *(const f32x4*)(xin + nb + (size_t)(oc^1)*HWSZ + pxi);
            f32x4 out4;
            #pragma unroll
            for (int j = 0; j < 4; ++j) {
                float yo = acc[mi][ni][j] + cbv + fmaf(c4[j], wsc, bsc);
                float yp = __shfl_xor(yo, 1);
                float xo = x4o[j], xp = x4p[j];
                if (FIRST) {
                    float sc = 1.f / fmaxf(sqrtf(xo*xo + xp*xp), 1e-12f);
                    xo *= sc; xp *= sc;
                }
                float inner = xo*yo + xp*yp;
                esum += inner;
                float rot  = (oc & 1) ?  xp : -xp;
                float rotp = (oc & 1) ? -xo :  xo;
                float xn  = xo + om*rot  + (yo - inner*xo);
                float xnp = xp + om*rotp + (yp - inner*xp);
                float sc2 = 1.f / fmaxf(sqrtf(xn*xn + xnp*xnp), 1e-12f);
                out4[j] = xn * sc2;
            }
            *(f32x4*)(xout + nb + (size_t)oc*HWSZ + pxi) = out4;
            if (WRITE_BF) {
                int py = pxi / 96, px = pxi - (pxi/96)*96;
                size_t o = ((size_t)b*PADA + (py+3)*PADW + (px+3))*128 + oc;
                #pragma unroll
                for (int j = 0; j < 4; ++j)
                    xbf_out[o + (size_t)j*128] = f2bf(out4[j]);
            }
        }
    }

    s_red[tid] = esum;
    __syncthreads();
    for (int s = 128; s > 0; s >>= 1) {
        if (tid < s) s_red[tid] += s_red[tid + s];
        __syncthreads();
    }
    if (tid == 0) atomicAdd(es + b, -0.5f * s_red[0]);
}

// ---------------------------------------------------------------------------
// Fallback (round-1 fp32 path) if ws is too small for the bf16 buffers.
// ---------------------------------------------------------------------------
template<bool FIRST>
__global__ __launch_bounds__(256) void conv_kur_kernel(
    const float* __restrict__ xin, const float* __restrict__ craw,
    const float* __restrict__ cw, const float* __restrict__ cb,
    const float* __restrict__ gnw, const float* __restrict__ gnb,
    const float* __restrict__ omega, const float* __restrict__ stats,
    float* __restrict__ xout, float* __restrict__ es)
{
    __shared__ float s_in[2][22][24];
    __shared__ float s_w[2][49][16];
    __shared__ float s_red[256];
    const int tid = threadIdx.x;
    const int tile = blockIdx.x, ocb = blockIdx.y, b = blockIdx.z;
    const int row0 = (tile / 6) * 16, col0 = (tile % 6) * 16;
    const int pxg = tid & 63, ocg = tid >> 6;
    const int ry = pxg >> 2, sx = pxg & 3;
    const size_t in_base = (size_t)b * CCH * HWSZ;
    float acc[4][4] = {};
    for (int icp = 0; icp < 64; ++icp) {
        __syncthreads();
        for (int idx = tid; idx < 968; idx += 256) {
            int ch = idx / 484, rem = idx - ch*484;
            int r = rem / 22, cl = rem - r*22;
            int gr = row0 + r - 3, gc = col0 + cl - 3;
            float v = 0.f;
            if (gr >= 0 && gr < IMG_H && gc >= 0 && gc < IMG_W)
                v = xin[in_base + (size_t)(icp*2 + ch)*HWSZ + gr*IMG_W + gc];
            s_in[ch][r][cl] = v;
        }
        {
            int combo = tid & 31, q = tid >> 5;
            if (q < 7) {
                int ch = combo >> 4, j = combo & 15;
                const float* wp = cw + ((size_t)(ocb*16 + j)*CCH + icp*2 + ch)*49 + q*7;
                #pragma unroll
                for (int t7 = 0; t7 < 7; ++t7) s_w[ch][q*7 + t7][j] = wp[t7];
            }
        }
        __syncthreads();
        if (FIRST) {
            for (int idx = tid; idx < 484; idx += 256) {
                int r = idx / 22, cl = idx - r*22;
                float v0 = s_in[0][r][cl], v1 = s_in[1][r][cl];
                float sc = 1.f / fmaxf(sqrtf(v0*v0 + v1*v1), 1e-12f);
                s_in[0][r][cl] = v0*sc; s_in[1][r][cl] = v1*sc;
            }
            __syncthreads();
        }
        #pragma unroll
        for (int ch = 0; ch < 2; ++ch)
            #pragma unroll
            for (int dy = 0; dy < 7; ++dy) {
                float r[12];
                const float* rp = &s_in[ch][ry + dy][sx*4];
                #pragma unroll
                for (int i = 0; i < 12; ++i) r[i] = rp[i];
                #pragma unroll
                for (int dx = 0; dx < 7; ++dx) {
                    const float* wv = &s_w[ch][dy*7 + dx][ocg*4];
                    float w0 = wv[0], w1 = wv[1], w2 = wv[2], w3 = wv[3];
                    #pragma unroll
                    for (int p = 0; p < 4; ++p) {
                        float iv = r[dx + p];
                        acc[0][p] = fmaf(w0, iv, acc[0][p]);
                        acc[1][p] = fmaf(w1, iv, acc[1][p]);
                        acc[2][p] = fmaf(w2, iv, acc[2][p]);
                        acc[3][p] = fmaf(w3, iv, acc[3][p]);
                    }
                }
            }
    }
    const int py = row0 + ry, px0 = col0 + sx*4;
    const float om = omega[0];
    const int ocbase = ocb*16 + ocg*4;
    float esum = 0.f;
    #pragma unroll
    for (int pr = 0; pr < 2; ++pr) {
        const int oc0 = ocbase + pr*2;
        const int g = oc0 >> 1;
        const float mu = stats[(b*64+g)*2], rs = stats[(b*64+g)*2+1];
        const float w0s = gnw[oc0]*rs,   b0s = gnb[oc0]   - mu*rs*gnw[oc0];
        const float w1s = gnw[oc0+1]*rs, b1s = gnb[oc0+1] - mu*rs*gnw[oc0+1];
        const float cb0 = cb[oc0], cb1 = cb[oc0+1];
        const size_t off = in_base + (size_t)oc0*HWSZ + py*IMG_W + px0;
        const float* c0p = craw + off; const float* c1p = c0p + HWSZ;
        const float* x0p = xin  + off; const float* x1p = x0p + HWSZ;
        float* o0p = xout + off; float* o1p = o0p + HWSZ;
        #pragma unroll
        for (int p = 0; p < 4; ++p) {
            float x0 = x0p[p], x1 = x1p[p];
            if (FIRST) {
                float sc = 1.f / fmaxf(sqrtf(x0*x0 + x1*x1), 1e-12f);
                x0 *= sc; x1 *= sc;
            }
            float y0 = acc[pr*2][p]   + cb0 + fmaf(c0p[p], w0s, b0s);
            float y1 = acc[pr*2+1][p] + cb1 + fmaf(c1p[p], w1s, b1s);
            float inner = x0*y0 + x1*y1;
            esum += inner;
            float xn0 = x0 - om*x1 + (y0 - inner*x0);
            float xn1 = x1 + om*x0 + (y1 - inner*x1);
            float sc2 = 1.f / fmaxf(sqrtf(xn0*xn0 + xn1*xn1), 1e-12f);
            o0p[p] = xn0*sc2; o1p[p] = xn1*sc2;
        }
    }
    s_red[tid] = esum;
    __syncthreads();
    for (int s = 128; s > 0; s >>= 1) {
        if (tid < s) s_red[tid] += s_red[tid + s];
        __syncthreads();
    }
    if (tid == 0) atomicAdd(es + b, -s_red[0]);
}

// ---------------------------------------------------------------------------
extern "C" void kernel_launch(void* const* d_in, const int* in_sizes, int n_in,
                              void* d_out, int out_size, void* d_ws, size_t ws_size,
                              hipStream_t stream)
{
    const float* x   = (const float*)d_in[0];
    const float* c   = (const float*)d_in[1];
    const float* cw  = (const float*)d_in[2];
    const float* cb  = (const float*)d_in[3];
    const float* gnw = (const float*)d_in[4];
    const float* gnb = (const float*)d_in[5];
    const float* om  = (const float*)d_in[6];
    float* out = (float*)d_out;

    const size_t OFF_WBF  = 4096;
    const size_t OFF_XBFA = 1609728;
    const size_t OFF_XBFB = 22917120;
    const size_t WS_NEED  = 44224512;

    float* stats = (float*)d_ws;
    hipMemsetAsync(out + ES_OFF, 0, 40 * sizeof(float), stream);
    gn_stats_kernel<<<512, 256, 0, stream>>>(c, stats);

    if (ws_size >= WS_NEED) {
        u16* wbf  = (u16*)((char*)d_ws + OFF_WBF);
        u16* xbfA = (u16*)((char*)d_ws + OFF_XBFA);
        u16* xbfB = (u16*)((char*)d_ws + OFF_XBFB);

        hipMemsetAsync(xbfA, 0, XBF_BYTES, stream);
        hipMemsetAsync(xbfB, 0, XBF_BYTES, stream);
        wprep_kernel<<<(128*128*49 + 255)/256, 256, 0, stream>>>(cw, wbf);
        xprep_kernel<<<(BATCH*HWSZ*64 + 255)/256, 256, 0, stream>>>(x, xbfA);

        dim3 grid(72, 8);
        // t=0: in xbfA, out xbfB
        convk<true, true><<<grid, 256, 0, stream>>>(xbfA, x, c, wbf, cb, gnw, gnb,
            om, stats, out + 0*(size_t)XS_ELEMS, xbfB, out + ES_OFF + 1*8);
        // t=1: in xbfB, out xbfA
        convk<false, true><<<grid, 256, 0, stream>>>(xbfB, out + 0*(size_t)XS_ELEMS,
            c, wbf, cb, gnw, gnb, om, stats, out + 1*(size_t)XS_ELEMS, xbfA,
            out + ES_OFF + 2*8);
        // t=2: in xbfA, out xbfB
        convk<false, true><<<grid, 256, 0, stream>>>(xbfA, out + 1*(size_t)XS_ELEMS,
            c, wbf, cb, gnw, gnb, om, stats, out + 2*(size_t)XS_ELEMS, xbfB,
            out + ES_OFF + 3*8);
        // t=3: in xbfB, no bf16 output needed
        convk<false, false><<<grid, 256, 0, stream>>>(xbfB, out + 2*(size_t)XS_ELEMS,
            c, wbf, cb, gnw, gnb, om, stats, out + 3*(size_t)XS_ELEMS, xbfA,
            out + ES_OFF + 4*8);
    } else {
        // fallback: fp32 VALU path (round-1)
        dim3 grid(36, 8, 8);
        const float* xin = x;
        for (int t = 0; t < NT; ++t) {
            float* xo  = out + (size_t)t * XS_ELEMS;
            float* esl = out + ES_OFF + (t + 1) * 8;
            if (t == 0)
                conv_kur_kernel<true ><<<grid, 256, 0, stream>>>(xin, c, cw, cb, gnw, gnb, om, stats, xo, esl);
            else
                conv_kur_kernel<false><<<grid, 256, 0, stream>>>(xin, c, cw, cb, gnw, gnb, om, stats, xo, esl);
            xin = xo;
        }
    }
}